// Round 7
// baseline (954.430 us; speedup 1.0000x reference)
//
#include <hip/hip_runtime.h>
#include <math.h>

#define Bn 8
#define Hn 256
#define Wn 256
#define HW (Hn * Wn)
#define ROWS 4
#define RPL 6   // rows per plane staged: ROWS + 2 halo
#define RP 264  // padded row length (words); data at [4..259], zeros at 3/260
#define ZW (12 * RP)  // zero region: rowsF[ZW .. ZW+63] == 0

typedef __attribute__((ext_vector_type(8))) short bf16x8;
typedef __attribute__((ext_vector_type(4))) float f32x4;
typedef __attribute__((ext_vector_type(2))) float f32x2;

__device__ __forceinline__ unsigned int pk_bits(unsigned int lo,
                                                unsigned int hi) {
  return __builtin_amdgcn_perm(hi, lo, 0x07060302u);
}
__device__ __forceinline__ unsigned int pk_bf16(float lo, float hi) {
  return pk_bits(__float_as_uint(lo), __float_as_uint(hi));
}
// packed fma: c + {s,s}*a  (fp-contract -> v_pk_fma_f32)
__device__ __forceinline__ f32x2 fma2(float s, f32x2 a, f32x2 c) {
  f32x2 sv = {s, s};
  return sv * a + c;
}

// k-slot -> tap mapping (tap = pl*9 + rr*3 + dx), bank-pairing preserved:
//   (pl,rr=0)<->(pl,rr=2): delta 2*RP = 528 == 16 (mod 32)
//   (pl0,rr=1)<->(pl1,rr=1): delta 6*RP = 1584 == 16 (mod 32)
__device__ __constant__ const int T0c[8] = {0, 1, 2, 9, 10, 11, 3, 4};
__device__ __constant__ const int T1c[8] = {6, 7, 8, 15, 16, 17, 12, 13};
__device__ __constant__ const int T2c[8] = {5, 14, -1, -1, -1, -1, -1, -1};

// Kernel A (R16): R15 core + transpose-reduce epilogue.
// DS-pipe theory: per wave-row DS = 16 gather ds_read2 + 1 ccv + 8 reduce
// (2 swz + 2 bperm per compute2) ~= 25; 12blk/CU x 4w x ~110 DS x ~6cy
// ~= 32K cycles == observed budget. All prior nulls (VALU/ILP/TLP/sched)
// are consistent with a shared-DS-pipe bound. This round removes 5 DS/row:
// butterfly transpose-reduce (2 bperm xor32 + 1 swz xor16) delivers gate
// l>>4 to lane l directly; sigmoid 1x/lane instead of 4x; select chain gone.
__global__ __launch_bounds__(256, 4) void sim_kernel(
    const float* __restrict__ x,   // (8,7,256,256)
    const float* __restrict__ W1,  // (6,64,2,3,3)
    const float* __restrict__ b1,  // (6,64)
    const float* __restrict__ W2,  // (6,1,64,1,1)
    const float* __restrict__ b2,  // (6,1)
    float* __restrict__ comb)      // (8,7,256,256)
{
  __shared__ float rowsF[12 * RP + 64];  // 12.9 KB rows + zero region
  __shared__ uint4 wq[4][64];            // 4 KB A-frags

  int bi = blockIdx.x;
  int n  = bi >> 9;            // 0..5  (512 blocks per n)
  int b  = (bi >> 6) & 7;      // 0..7
  int h0 = (bi & 63) * ROWS;   // chunk start row
  int cc = (n < 3) ? n : n + 1;
  int t = threadIdx.x;

  const float* xb     = x + (size_t)b * 7 * HW;
  const float* basep  = xb + 3 * HW;
  const float* checkp = xb + (size_t)cc * HW;

  // ---- stage weights in MFMA A-layout with the k-remap ----
  {
    int f = t >> 6, qq = (t >> 4) & 3, m = t & 15;
    int bsrc = (n < 3) ? 0 : 1;  // weight input-ch that multiplies BASE
    const float* wch = W1 + ((size_t)(n * 64 + 16 * f + m)) * 18;
    unsigned int kv[4];
#pragma unroll
    for (int jj = 0; jj < 4; ++jj) {
      int ja = 2 * jj, jb = 2 * jj + 1;
      int ta = (qq == 0) ? T0c[ja] : (qq == 1) ? T1c[ja]
               : (qq == 2) ? T2c[ja] : -1;
      int tb = (qq == 0) ? T0c[jb] : (qq == 1) ? T1c[jb]
               : (qq == 2) ? T2c[jb] : -1;
      float va = 0.f, vb = 0.f;
      if (ta >= 0) {
        int pl = ta / 9, rem = ta - pl * 9;
        va = wch[(pl ? 1 - bsrc : bsrc) * 9 + rem];
      }
      if (tb >= 0) {
        int pl = tb / 9, rem = tb - pl * 9;
        vb = wch[(pl ? 1 - bsrc : bsrc) * 9 + rem];
      }
      kv[jj] = pk_bf16(va, vb);
    }
    wq[f][(qq << 4) + m] = make_uint4(kv[0], kv[1], kv[2], kv[3]);
  }

  // ---- per-lane conv2/bias params (global loads, no LDS dep) ----
  int lane = t & 63, wvid = t >> 6;
  int q = lane >> 4, m_ = lane & 15;
  f32x2 w2A[4], w2B[4];
  f32x4 b1vv[4];
#pragma unroll
  for (int f = 0; f < 4; ++f) {
    float4 tw = *(const float4*)&W2[n * 64 + 16 * f + 4 * q];
    float4 tb = *(const float4*)&b1[n * 64 + 16 * f + 4 * q];
    w2A[f][0] = tw.x; w2A[f][1] = tw.y;
    w2B[f][0] = tw.z; w2B[f][1] = tw.w;
    b1vv[f][0] = tb.x; b1vv[f][1] = tb.y;
    b1vv[f][2] = tb.z; b1vv[f][3] = tb.w;
  }
  float bbl = b2[n] * -1.442695041f;  // bias pre-folded into exp2 fma

  // ---- stage raw rows: 12 rows x 256 cols -> rowsF[rf*RP + 4 + col] ----
  {
    int col = (t & 63) << 2;
#pragma unroll
    for (int it = 0; it < 3; ++it) {
      int rf = it * 4 + (t >> 6);  // 0..11
      int pl = (rf >= RPL) ? 1 : 0;
      int j  = rf - pl * RPL;
      int hh = h0 - 1 + j;
      const float* src = pl ? checkp : basep;
      float4 val = make_float4(0.f, 0.f, 0.f, 0.f);
      if ((unsigned)hh < (unsigned)Hn)
        val = *(const float4*)(src + hh * Wn + col);
      *(float4*)&rowsF[rf * RP + 4 + col] = val;
    }
    if (t < 12) {  // edge zeros
      rowsF[t * RP + 3] = 0.f;
      rowsF[t * RP + 260] = 0.f;
    }
    if (t >= 192) rowsF[ZW + (t - 192)] = 0.f;  // zero region (64 words)
  }

  // ---- per-lane gather table: slot jh (k = 8q + jh) ----
  const unsigned int* rowsU = (const unsigned int*)rowsF;
  unsigned int addr[8];
#pragma unroll
  for (int jh = 0; jh < 8; ++jh) {
    int tap = (q == 0) ? T0c[jh] : (q == 1) ? T1c[jh]
              : (q == 2) ? T2c[jh] : -1;
    if (tap >= 0) {
      int pl = tap / 9, rem = tap - pl * 9;
      int rr = rem / 3, dx = rem - rr * 3;
      addr[jh] = (pl * RPL + rr) * RP + 3 + dx + wvid * 64 + m_;
    } else {
      addr[jh] = (unsigned)ZW;  // zero region; +16/32/48 also zero
    }
  }
  unsigned int stepA = (q <= 2) ? (unsigned)RP : 0u;
  unsigned int stepB = (q < 2) ? (unsigned)RP : 0u;
  int bpaddr = ((lane ^ 32) << 2);  // ds_bpermute byte address for xor32

  __syncthreads();

  // A fragments (contiguous 16 B per lane, conflict-free)
  bf16x8 afrag[4];
#pragma unroll
  for (int f = 0; f < 4; ++f) afrag[f] = *(const bf16x8*)&wq[f][lane];

  float* combcc = comb + ((size_t)b * 7 + cc) * HW;
  int pxs = wvid * 64 + lane;
  bool bb1 = (lane & 32) != 0;
  bool bb0 = (lane & 16) != 0;

  // dot partials for one strip pair; NO cross-lane reduce here.
  auto dots2 = [&](const unsigned int* dbuf, float& pA, float& pB) {
    union { unsigned int u[4]; bf16x8 v; } p0, p1;
#pragma unroll
    for (int jj = 0; jj < 4; ++jj) {
      p0.u[jj] = pk_bits(dbuf[2 * jj], dbuf[2 * jj + 1]);
      p1.u[jj] = pk_bits(dbuf[8 + 2 * jj], dbuf[8 + 2 * jj + 1]);
    }
    f32x4 acc0[4], acc1[4];
#pragma unroll
    for (int f = 0; f < 4; ++f) {
      acc0[f] = __builtin_amdgcn_mfma_f32_16x16x32_bf16(afrag[f], p0.v,
                                                        b1vv[f], 0, 0, 0);
      acc1[f] = __builtin_amdgcn_mfma_f32_16x16x32_bf16(afrag[f], p1.v,
                                                        b1vv[f], 0, 0, 0);
    }
    f32x2 sA0 = {0.f, 0.f}, sB0 = {0.f, 0.f};
    f32x2 sA1 = {0.f, 0.f}, sB1 = {0.f, 0.f};
#pragma unroll
    for (int f = 0; f < 4; ++f) {
      f32x2 a01, a23, c01, c23;
      a01[0] = acc0[f][0]; a01[1] = acc0[f][1];
      a23[0] = acc0[f][2]; a23[1] = acc0[f][3];
      c01[0] = acc1[f][0]; c01[1] = acc1[f][1];
      c23[0] = acc1[f][2]; c23[1] = acc1[f][3];
      a01 = __builtin_elementwise_max(a01, (f32x2)0.f);
      a23 = __builtin_elementwise_max(a23, (f32x2)0.f);
      c01 = __builtin_elementwise_max(c01, (f32x2)0.f);
      c23 = __builtin_elementwise_max(c23, (f32x2)0.f);
      sA0 += w2A[f] * a01;
      sB0 += w2B[f] * a23;
      sA1 += w2A[f] * c01;
      sB1 += w2B[f] * c23;
    }
    f32x2 s0 = sA0 + sB0, s1 = sA1 + sB1;  // pk add
    pA = s0[0] + s0[1];
    pB = s1[0] + s1[1];
  };

  unsigned int bufA[16], bufB[16];
#pragma unroll
  for (int jh = 0; jh < 8; ++jh) {
    bufA[jh]     = rowsU[addr[jh]];
    bufA[jh + 8] = rowsU[addr[jh] + 16];
  }

#pragma unroll 1
  for (int r = 0; r < ROWS; ++r) {
    float ccv = rowsF[(RPL + r + 1) * RP + 4 + pxs];  // check center (early)

#pragma unroll
    for (int jh = 0; jh < 8; ++jh) {
      bufB[jh]     = rowsU[addr[jh] + 32];
      bufB[jh + 8] = rowsU[addr[jh] + 48];
    }

    float P0, P1, P2, P3;
    dots2(bufA, P0, P1);

    if (r < ROWS - 1) {
#pragma unroll
      for (int jh = 0; jh < 8; ++jh) {
        addr[jh] += (jh < 2) ? stepA : stepB;
        bufA[jh]     = rowsU[addr[jh]];
        bufA[jh + 8] = rowsU[addr[jh] + 16];
      }
    }

    dots2(bufB, P2, P3);

    // Butterfly transpose-reduce: lane l ends with gate g = l>>4 summed
    // over the 4 q-groups. Step 1 (xor32, payload 2): accumulate over b1.
    float U0 = bb1 ? P0 : P2;   // what the partner half needs
    float U1 = bb1 ? P1 : P3;
    float r0 = __int_as_float(
        __builtin_amdgcn_ds_bpermute(bpaddr, __float_as_int(U0)));
    float r1 = __int_as_float(
        __builtin_amdgcn_ds_bpermute(bpaddr, __float_as_int(U1)));
    float T0 = (bb1 ? P2 : P0) + r0;
    float T1 = (bb1 ? P3 : P1) + r1;
    // Step 2 (xor16, payload 1): accumulate over b0.
    float Wv = bb0 ? T0 : T1;   // partner needs T[!b0]
    float r2 = __int_as_float(
        __builtin_amdgcn_ds_swizzle(__float_as_int(Wv), 0x401F));
    float S = (bb0 ? T1 : T0) + r2;

    float e = __builtin_amdgcn_exp2f(fmaf(S, -1.442695041f, bbl));
    float g = __builtin_amdgcn_rcpf(1.f + e);
    combcc[(h0 + r) * Wn + pxs] = g * ccv;
  }
}

// Kernel B (R16): mix conv (7->7, 3x3, SAME). R13 geometry (512 blocks,
// 512 thr, 4-row chunks, LDS 44.4 KB -> 3 blk/CU possible, TLP restored)
// + packed v_pk_fma_f32 (R15 showed the packed win was real but was
// cancelled by its occupancy loss: -VALU -8us, -TLP +10.7us).
// DS reads unchanged vs R13 (2x ds_read2 per (ic,dy)).
__global__ __launch_bounds__(512) void mix_kernel(
    const float* __restrict__ comb,  // (8,7,256,256), plane 3 unused
    const float* __restrict__ x,     // (8,7,256,256), plane 3 = base
    const float* __restrict__ Wm,    // (7,7,3,3)
    const float* __restrict__ bm,    // (7,)
    float* __restrict__ out)         // (8,7,256,256)
{
  __shared__ float mr[42 * RP];  // 44.4 KB

  int bi = blockIdx.x;           // 0..511
  int b  = bi >> 6;
  int h0 = (bi & 63) << 2;
  int t = threadIdx.x;

  // stage: 42 rows (ic*6 + j) x 64 float4
  for (int u = t; u < 42 * 64; u += 512) {
    int rf = u >> 6;             // 0..41 = ic*6 + j
    int col = (u & 63) << 2;
    int ic = rf / 6, j = rf - ic * 6;
    int hh = h0 - 1 + j;
    const float* src = (ic == 3) ? (x + ((size_t)b * 7 + 3) * HW)
                                 : (comb + ((size_t)b * 7 + ic) * HW);
    float4 v = make_float4(0.f, 0.f, 0.f, 0.f);
    if ((unsigned)hh < (unsigned)Hn)
      v = *(const float4*)(src + hh * Wn + col);
    *(float4*)&mr[rf * RP + 4 + col] = v;
  }
  if (t < 42) {
    mr[t * RP + 3] = 0.f;
    mr[t * RP + 260] = 0.f;
  }
  __syncthreads();

  int r   = t >> 7;           // local row 0..3
  int px0 = (t & 127) << 1;   // 0..254
  int h   = h0 + r;

  f32x2 acc[7];
#pragma unroll
  for (int oc = 0; oc < 7; ++oc) {
    float bv = bm[oc];
    acc[oc] = (f32x2){bv, bv};
  }

#pragma unroll 1
  for (int ic = 0; ic < 7; ++ic) {
    // tap pairs: PP[dy][k] = (v_k, v_{k+1}), k=0..2, from 4 scalars
    f32x2 PP[3][3];
#pragma unroll
    for (int dy = 0; dy < 3; ++dy) {
      const float* rp = &mr[(ic * 6 + r + dy) * RP + 3 + px0];
      float v0 = rp[0], v1 = rp[1], v2 = rp[2], v3 = rp[3];
      PP[dy][0] = (f32x2){v0, v1};
      PP[dy][1] = (f32x2){v1, v2};
      PP[dy][2] = (f32x2){v2, v3};
    }
    const float* wp = Wm + ic * 9;
#pragma unroll
    for (int oc = 0; oc < 7; ++oc) {
      const float* wo = wp + oc * 63;
#pragma unroll
      for (int dy = 0; dy < 3; ++dy) {
        float w0 = wo[dy * 3], w1 = wo[dy * 3 + 1], w2 = wo[dy * 3 + 2];
        acc[oc] = fma2(w0, PP[dy][0],
                   fma2(w1, PP[dy][1], fma2(w2, PP[dy][2], acc[oc])));
      }
    }
  }

  float* ob = out + (size_t)b * 7 * HW + h * Wn + px0;
#pragma unroll
  for (int oc = 0; oc < 7; ++oc)
    *(float2*)(ob + (size_t)oc * HW) = make_float2(acc[oc][0], acc[oc][1]);
}

extern "C" void kernel_launch(void* const* d_in, const int* in_sizes, int n_in,
                              void* d_out, int out_size, void* d_ws, size_t ws_size,
                              hipStream_t stream) {
  const float* x  = (const float*)d_in[0];
  const float* W1 = (const float*)d_in[1];
  const float* b1 = (const float*)d_in[2];
  const float* W2 = (const float*)d_in[3];
  const float* b2 = (const float*)d_in[4];
  const float* Wm = (const float*)d_in[5];
  const float* bm = (const float*)d_in[6];
  float* out  = (float*)d_out;
  float* comb = (float*)d_ws;  // 8*7*256*256 floats = 14.7 MB

  sim_kernel<<<6 * 8 * (Hn / ROWS), 256, 0, stream>>>(x, W1, b1, W2, b2, comb);
  mix_kernel<<<8 * (Hn / 4), 512, 0, stream>>>(comb, x, Wm, bm, out);
}

// Round 8
// 113.196 us; speedup vs baseline: 8.4316x; 8.4316x over previous
//
#include <hip/hip_runtime.h>
#include <math.h>

#define Bn 8
#define Hn 256
#define Wn 256
#define HW (Hn * Wn)
#define ROWS 4
#define RPL 6   // rows per plane staged: ROWS + 2 halo
#define RP 264  // padded row length (words); data at [4..259], zeros at 3/260
#define ZW (12 * RP)  // zero region: rowsF[ZW .. ZW+63] == 0

typedef __attribute__((ext_vector_type(8))) short bf16x8;
typedef __attribute__((ext_vector_type(4))) float f32x4;
typedef __attribute__((ext_vector_type(2))) float f32x2;

__device__ __forceinline__ unsigned int pk_bits(unsigned int lo,
                                                unsigned int hi) {
  return __builtin_amdgcn_perm(hi, lo, 0x07060302u);
}
__device__ __forceinline__ unsigned int pk_bf16(float lo, float hi) {
  return pk_bits(__float_as_uint(lo), __float_as_uint(hi));
}
// packed fma: c + {s,s}*a  (fp-contract -> v_pk_fma_f32)
__device__ __forceinline__ f32x2 fma2(float s, f32x2 a, f32x2 c) {
  f32x2 sv = {s, s};
  return sv * a + c;
}

// k-slot -> tap mapping (tap = pl*9 + rr*3 + dx), bank-pairing preserved:
//   (pl,rr=0)<->(pl,rr=2): delta 2*RP = 528 == 16 (mod 32)
//   (pl0,rr=1)<->(pl1,rr=1): delta 6*RP = 1584 == 16 (mod 32)
__device__ __constant__ const int T0c[8] = {0, 1, 2, 9, 10, 11, 3, 4};
__device__ __constant__ const int T1c[8] = {6, 7, 8, 15, 16, 17, 12, 13};
__device__ __constant__ const int T2c[8] = {5, 14, -1, -1, -1, -1, -1, -1};

// Kernel A (R17): R16's butterfly transpose-reduce (harness-verified), but
// SCRATCH-PROOF: R16 spilled bufA/bufB to scratch (WRITE 2.5GB, 881us).
// Fix: no local arrays at all -- LDS reads issued directly at use inside
// dots2(woff) (R11-R13 proved the compiler re-sinks prefetch buffers
// anyway). DS per wave-row: 16 gather + 1 ccv + 3 reduce (2 bperm + 1 swz)
// vs 25 in R13; sigmoid 1x/lane; select chain gone.
__global__ __launch_bounds__(256, 4) void sim_kernel(
    const float* __restrict__ x,   // (8,7,256,256)
    const float* __restrict__ W1,  // (6,64,2,3,3)
    const float* __restrict__ b1,  // (6,64)
    const float* __restrict__ W2,  // (6,1,64,1,1)
    const float* __restrict__ b2,  // (6,1)
    float* __restrict__ comb)      // (8,7,256,256)
{
  __shared__ float rowsF[12 * RP + 64];  // 12.9 KB rows + zero region
  __shared__ uint4 wq[4][64];            // 4 KB A-frags

  int bi = blockIdx.x;
  int n  = bi >> 9;            // 0..5  (512 blocks per n)
  int b  = (bi >> 6) & 7;      // 0..7
  int h0 = (bi & 63) * ROWS;   // chunk start row
  int cc = (n < 3) ? n : n + 1;
  int t = threadIdx.x;

  const float* xb     = x + (size_t)b * 7 * HW;
  const float* basep  = xb + 3 * HW;
  const float* checkp = xb + (size_t)cc * HW;

  // ---- stage weights in MFMA A-layout with the k-remap ----
  {
    int f = t >> 6, qq = (t >> 4) & 3, m = t & 15;
    int bsrc = (n < 3) ? 0 : 1;  // weight input-ch that multiplies BASE
    const float* wch = W1 + ((size_t)(n * 64 + 16 * f + m)) * 18;
    unsigned int kv[4];
#pragma unroll
    for (int jj = 0; jj < 4; ++jj) {
      int ja = 2 * jj, jb = 2 * jj + 1;
      int ta = (qq == 0) ? T0c[ja] : (qq == 1) ? T1c[ja]
               : (qq == 2) ? T2c[ja] : -1;
      int tb = (qq == 0) ? T0c[jb] : (qq == 1) ? T1c[jb]
               : (qq == 2) ? T2c[jb] : -1;
      float va = 0.f, vb = 0.f;
      if (ta >= 0) {
        int pl = ta / 9, rem = ta - pl * 9;
        va = wch[(pl ? 1 - bsrc : bsrc) * 9 + rem];
      }
      if (tb >= 0) {
        int pl = tb / 9, rem = tb - pl * 9;
        vb = wch[(pl ? 1 - bsrc : bsrc) * 9 + rem];
      }
      kv[jj] = pk_bf16(va, vb);
    }
    wq[f][(qq << 4) + m] = make_uint4(kv[0], kv[1], kv[2], kv[3]);
  }

  // ---- per-lane conv2/bias params (global loads, no LDS dep) ----
  int lane = t & 63, wvid = t >> 6;
  int q = lane >> 4, m_ = lane & 15;
  f32x2 w2A[4], w2B[4];
  f32x4 b1vv[4];
#pragma unroll
  for (int f = 0; f < 4; ++f) {
    float4 tw = *(const float4*)&W2[n * 64 + 16 * f + 4 * q];
    float4 tb = *(const float4*)&b1[n * 64 + 16 * f + 4 * q];
    w2A[f][0] = tw.x; w2A[f][1] = tw.y;
    w2B[f][0] = tw.z; w2B[f][1] = tw.w;
    b1vv[f][0] = tb.x; b1vv[f][1] = tb.y;
    b1vv[f][2] = tb.z; b1vv[f][3] = tb.w;
  }
  float bbl = b2[n] * -1.442695041f;  // bias pre-folded into exp2 fma

  // ---- stage raw rows: 12 rows x 256 cols -> rowsF[rf*RP + 4 + col] ----
  {
    int col = (t & 63) << 2;
#pragma unroll
    for (int it = 0; it < 3; ++it) {
      int rf = it * 4 + (t >> 6);  // 0..11
      int pl = (rf >= RPL) ? 1 : 0;
      int j  = rf - pl * RPL;
      int hh = h0 - 1 + j;
      const float* src = pl ? checkp : basep;
      float4 val = make_float4(0.f, 0.f, 0.f, 0.f);
      if ((unsigned)hh < (unsigned)Hn)
        val = *(const float4*)(src + hh * Wn + col);
      *(float4*)&rowsF[rf * RP + 4 + col] = val;
    }
    if (t < 12) {  // edge zeros
      rowsF[t * RP + 3] = 0.f;
      rowsF[t * RP + 260] = 0.f;
    }
    if (t >= 192) rowsF[ZW + (t - 192)] = 0.f;  // zero region (64 words)
  }

  // ---- per-lane gather table: slot jh (k = 8q + jh) ----
  const unsigned int* rowsU = (const unsigned int*)rowsF;
  unsigned int addr[8];
#pragma unroll
  for (int jh = 0; jh < 8; ++jh) {
    int tap = (q == 0) ? T0c[jh] : (q == 1) ? T1c[jh]
              : (q == 2) ? T2c[jh] : -1;
    if (tap >= 0) {
      int pl = tap / 9, rem = tap - pl * 9;
      int rr = rem / 3, dx = rem - rr * 3;
      addr[jh] = (pl * RPL + rr) * RP + 3 + dx + wvid * 64 + m_;
    } else {
      addr[jh] = (unsigned)ZW;  // zero region; +16/32/48 also zero
    }
  }
  unsigned int stepA = (q <= 2) ? (unsigned)RP : 0u;
  unsigned int stepB = (q < 2) ? (unsigned)RP : 0u;
  int bpaddr = ((lane ^ 32) << 2);  // ds_bpermute byte address for xor32

  __syncthreads();

  // A fragments (contiguous 16 B per lane, conflict-free)
  bf16x8 afrag[4];
#pragma unroll
  for (int f = 0; f < 4; ++f) afrag[f] = *(const bf16x8*)&wq[f][lane];

  float* combcc = comb + ((size_t)b * 7 + cc) * HW;
  int pxs = wvid * 64 + lane;
  bool bb1 = (lane & 32) != 0;
  bool bb0 = (lane & 16) != 0;

  // dot partials for strip pair at word offset woff (0 or 32); LDS reads
  // issued directly (no spillable local arrays).
  auto dots2 = [&](unsigned int woff, float& pA, float& pB) {
    union { unsigned int u[4]; bf16x8 v; } p0, p1;
#pragma unroll
    for (int jj = 0; jj < 4; ++jj) {
      p0.u[jj] = pk_bits(rowsU[addr[2 * jj] + woff],
                         rowsU[addr[2 * jj + 1] + woff]);
      p1.u[jj] = pk_bits(rowsU[addr[2 * jj] + woff + 16],
                         rowsU[addr[2 * jj + 1] + woff + 16]);
    }
    f32x4 acc0[4], acc1[4];
#pragma unroll
    for (int f = 0; f < 4; ++f) {
      acc0[f] = __builtin_amdgcn_mfma_f32_16x16x32_bf16(afrag[f], p0.v,
                                                        b1vv[f], 0, 0, 0);
      acc1[f] = __builtin_amdgcn_mfma_f32_16x16x32_bf16(afrag[f], p1.v,
                                                        b1vv[f], 0, 0, 0);
    }
    f32x2 sA0 = {0.f, 0.f}, sB0 = {0.f, 0.f};
    f32x2 sA1 = {0.f, 0.f}, sB1 = {0.f, 0.f};
#pragma unroll
    for (int f = 0; f < 4; ++f) {
      f32x2 a01, a23, c01, c23;
      a01[0] = acc0[f][0]; a01[1] = acc0[f][1];
      a23[0] = acc0[f][2]; a23[1] = acc0[f][3];
      c01[0] = acc1[f][0]; c01[1] = acc1[f][1];
      c23[0] = acc1[f][2]; c23[1] = acc1[f][3];
      a01 = __builtin_elementwise_max(a01, (f32x2)0.f);
      a23 = __builtin_elementwise_max(a23, (f32x2)0.f);
      c01 = __builtin_elementwise_max(c01, (f32x2)0.f);
      c23 = __builtin_elementwise_max(c23, (f32x2)0.f);
      sA0 += w2A[f] * a01;
      sB0 += w2B[f] * a23;
      sA1 += w2A[f] * c01;
      sB1 += w2B[f] * c23;
    }
    f32x2 s0 = sA0 + sB0, s1 = sA1 + sB1;  // pk add
    pA = s0[0] + s0[1];
    pB = s1[0] + s1[1];
  };

#pragma unroll 1
  for (int r = 0; r < ROWS; ++r) {
    float ccv = rowsF[(RPL + r + 1) * RP + 4 + pxs];  // check center (early)

    float P0, P1, P2, P3;
    dots2(0u, P0, P1);
    dots2(32u, P2, P3);

    // Butterfly transpose-reduce (harness-verified in R16): lane l ends
    // with gate l>>4 fully reduced over the 4 q-groups.
    float U0 = bb1 ? P0 : P2;   // what the partner half needs
    float U1 = bb1 ? P1 : P3;
    float r0 = __int_as_float(
        __builtin_amdgcn_ds_bpermute(bpaddr, __float_as_int(U0)));
    float r1 = __int_as_float(
        __builtin_amdgcn_ds_bpermute(bpaddr, __float_as_int(U1)));
    float T0 = (bb1 ? P2 : P0) + r0;
    float T1 = (bb1 ? P3 : P1) + r1;
    float Wv = bb0 ? T0 : T1;   // partner needs T[!b0]
    float r2 = __int_as_float(
        __builtin_amdgcn_ds_swizzle(__float_as_int(Wv), 0x401F));
    float S = (bb0 ? T1 : T0) + r2;

    float e = __builtin_amdgcn_exp2f(fmaf(S, -1.442695041f, bbl));
    float g = __builtin_amdgcn_rcpf(1.f + e);
    combcc[(h0 + r) * Wn + pxs] = g * ccv;

    if (r < ROWS - 1) {
#pragma unroll
      for (int jh = 0; jh < 8; ++jh) addr[jh] += (jh < 2) ? stepA : stepB;
    }
  }
}

// Kernel B (R16 mix, kept): mix conv (7->7, 3x3, SAME). R13 geometry
// (512 blocks, 512 thr, 4-row chunks, LDS 44.4 KB) + packed v_pk_fma_f32
// (R15: packed win real but was cancelled by its occupancy loss; here TLP
// is restored). DS reads unchanged vs R13.
__global__ __launch_bounds__(512) void mix_kernel(
    const float* __restrict__ comb,  // (8,7,256,256), plane 3 unused
    const float* __restrict__ x,     // (8,7,256,256), plane 3 = base
    const float* __restrict__ Wm,    // (7,7,3,3)
    const float* __restrict__ bm,    // (7,)
    float* __restrict__ out)         // (8,7,256,256)
{
  __shared__ float mr[42 * RP];  // 44.4 KB

  int bi = blockIdx.x;           // 0..511
  int b  = bi >> 6;
  int h0 = (bi & 63) << 2;
  int t = threadIdx.x;

  // stage: 42 rows (ic*6 + j) x 64 float4
  for (int u = t; u < 42 * 64; u += 512) {
    int rf = u >> 6;             // 0..41 = ic*6 + j
    int col = (u & 63) << 2;
    int ic = rf / 6, j = rf - ic * 6;
    int hh = h0 - 1 + j;
    const float* src = (ic == 3) ? (x + ((size_t)b * 7 + 3) * HW)
                                 : (comb + ((size_t)b * 7 + ic) * HW);
    float4 v = make_float4(0.f, 0.f, 0.f, 0.f);
    if ((unsigned)hh < (unsigned)Hn)
      v = *(const float4*)(src + hh * Wn + col);
    *(float4*)&mr[rf * RP + 4 + col] = v;
  }
  if (t < 42) {
    mr[t * RP + 3] = 0.f;
    mr[t * RP + 260] = 0.f;
  }
  __syncthreads();

  int r   = t >> 7;           // local row 0..3
  int px0 = (t & 127) << 1;   // 0..254
  int h   = h0 + r;

  f32x2 acc[7];
#pragma unroll
  for (int oc = 0; oc < 7; ++oc) {
    float bv = bm[oc];
    acc[oc] = (f32x2){bv, bv};
  }

#pragma unroll 1
  for (int ic = 0; ic < 7; ++ic) {
    // tap pairs: PP[dy][k] = (v_k, v_{k+1}), k=0..2, from 4 scalars
    f32x2 PP[3][3];
#pragma unroll
    for (int dy = 0; dy < 3; ++dy) {
      const float* rp = &mr[(ic * 6 + r + dy) * RP + 3 + px0];
      float v0 = rp[0], v1 = rp[1], v2 = rp[2], v3 = rp[3];
      PP[dy][0] = (f32x2){v0, v1};
      PP[dy][1] = (f32x2){v1, v2};
      PP[dy][2] = (f32x2){v2, v3};
    }
    const float* wp = Wm + ic * 9;
#pragma unroll
    for (int oc = 0; oc < 7; ++oc) {
      const float* wo = wp + oc * 63;
#pragma unroll
      for (int dy = 0; dy < 3; ++dy) {
        float w0 = wo[dy * 3], w1 = wo[dy * 3 + 1], w2 = wo[dy * 3 + 2];
        acc[oc] = fma2(w0, PP[dy][0],
                   fma2(w1, PP[dy][1], fma2(w2, PP[dy][2], acc[oc])));
      }
    }
  }

  float* ob = out + (size_t)b * 7 * HW + h * Wn + px0;
#pragma unroll
  for (int oc = 0; oc < 7; ++oc)
    *(float2*)(ob + (size_t)oc * HW) = make_float2(acc[oc][0], acc[oc][1]);
}

extern "C" void kernel_launch(void* const* d_in, const int* in_sizes, int n_in,
                              void* d_out, int out_size, void* d_ws, size_t ws_size,
                              hipStream_t stream) {
  const float* x  = (const float*)d_in[0];
  const float* W1 = (const float*)d_in[1];
  const float* b1 = (const float*)d_in[2];
  const float* W2 = (const float*)d_in[3];
  const float* b2 = (const float*)d_in[4];
  const float* Wm = (const float*)d_in[5];
  const float* bm = (const float*)d_in[6];
  float* out  = (float*)d_out;
  float* comb = (float*)d_ws;  // 8*7*256*256 floats = 14.7 MB

  sim_kernel<<<6 * 8 * (Hn / ROWS), 256, 0, stream>>>(x, W1, b1, W2, b2, comb);
  mix_kernel<<<8 * (Hn / 4), 512, 0, stream>>>(comb, x, Wm, bm, out);
}

// Round 9
// 112.777 us; speedup vs baseline: 8.4630x; 1.0037x over previous
//
#include <hip/hip_runtime.h>
#include <math.h>

#define Bn 8
#define Hn 256
#define Wn 256
#define HW (Hn * Wn)
#define ROWS 4
#define RPL 6   // rows per plane staged: ROWS + 2 halo
#define RP 264  // padded row length (words); data at [4..259], zeros at 3/260
#define ZW (12 * RP)  // zero region: rowsF[ZW .. ZW+63] == 0

typedef __attribute__((ext_vector_type(8))) short bf16x8;
typedef __attribute__((ext_vector_type(4))) float f32x4;
typedef __attribute__((ext_vector_type(2))) float f32x2;

__device__ __forceinline__ unsigned int pk_bits(unsigned int lo,
                                                unsigned int hi) {
  return __builtin_amdgcn_perm(hi, lo, 0x07060302u);
}
__device__ __forceinline__ unsigned int pk_bf16(float lo, float hi) {
  return pk_bits(__float_as_uint(lo), __float_as_uint(hi));
}
// packed fma: c + {s,s}*a  (fp-contract -> v_pk_fma_f32)
__device__ __forceinline__ f32x2 fma2(float s, f32x2 a, f32x2 c) {
  f32x2 sv = {s, s};
  return sv * a + c;
}

// R18 k-slot map: lane q owns two (pl,dx) groups, rr in consecutive slots:
//   q0: g0=(pl0,dx0) g1=(pl0,dx1); q1: g0=(pl0,dx2) g1=(pl1,dx0);
//   q2: g0=(pl1,dx1) g1=(pl1,dx2); q3 + slots jh3/jh7: dead (A-weight 0).
// Slots jh0-2 = g0 rr0-2, jh3 = pad; jh4-6 = g1 rr0-2, jh7 = pad.
// => per row each lane reads ONE new input row per group (rr rotate in
// regs): 4 ds_read2_b32/row (4 strips x 2 groups) vs 16 before.

// Kernel A (R18): rolling-register gather. R17 (113.2us total, first real
// win) confirmed DS-issue-bound: -5 DS/row -> -3.3us. This round: gather
// re-reads eliminated via row-rotation; DS/row 20 -> 8 (4 gather + 1 ccv
// + 3 reduce). All rolling state statically indexed, no pointer-passed
// arrays (R16 scratch lesson). Butterfly reduce unchanged (verified).
__global__ __launch_bounds__(256, 4) void sim_kernel(
    const float* __restrict__ x,   // (8,7,256,256)
    const float* __restrict__ W1,  // (6,64,2,3,3)
    const float* __restrict__ b1,  // (6,64)
    const float* __restrict__ W2,  // (6,1,64,1,1)
    const float* __restrict__ b2,  // (6,1)
    float* __restrict__ comb)      // (8,7,256,256)
{
  __shared__ float rowsF[12 * RP + 64];  // 12.9 KB rows + zero region
  __shared__ uint4 wq[4][64];            // 4 KB A-frags

  int bi = blockIdx.x;
  int n  = bi >> 9;            // 0..5  (512 blocks per n)
  int b  = (bi >> 6) & 7;      // 0..7
  int h0 = (bi & 63) * ROWS;   // chunk start row
  int cc = (n < 3) ? n : n + 1;
  int t = threadIdx.x;

  const float* xb     = x + (size_t)b * 7 * HW;
  const float* basep  = xb + 3 * HW;
  const float* checkp = xb + (size_t)cc * HW;

  // ---- stage weights in MFMA A-layout (R18 slot map) ----
  {
    int f = t >> 6, qq = (t >> 4) & 3, m = t & 15;
    int bsrc = (n < 3) ? 0 : 1;  // weight input-ch that multiplies BASE
    const float* wch = W1 + ((size_t)(n * 64 + 16 * f + m)) * 18;
    int g0pl = (qq == 2) ? 1 : 0;
    int g0dx = (qq == 0) ? 0 : (qq == 1) ? 2 : 1;
    int g1pl = (qq == 0) ? 0 : 1;
    int g1dx = (qq == 0) ? 1 : (qq == 1) ? 0 : 2;
    float wg0[3], wg1[3];
#pragma unroll
    for (int rrs = 0; rrs < 3; ++rrs) {
      wg0[rrs] = (qq <= 2)
          ? wch[(g0pl ? 1 - bsrc : bsrc) * 9 + rrs * 3 + g0dx] : 0.f;
      wg1[rrs] = (qq <= 2)
          ? wch[(g1pl ? 1 - bsrc : bsrc) * 9 + rrs * 3 + g1dx] : 0.f;
    }
    unsigned int kv[4];
    kv[0] = pk_bf16(wg0[0], wg0[1]);
    kv[1] = pk_bf16(wg0[2], 0.f);     // pad slot jh3: A = 0
    kv[2] = pk_bf16(wg1[0], wg1[1]);
    kv[3] = pk_bf16(wg1[2], 0.f);     // pad slot jh7: A = 0
    wq[f][(qq << 4) + m] = make_uint4(kv[0], kv[1], kv[2], kv[3]);
  }

  // ---- per-lane conv2/bias params (global loads, no LDS dep) ----
  int lane = t & 63, wvid = t >> 6;
  int q = lane >> 4, m_ = lane & 15;
  f32x2 w2A[4], w2B[4];
  f32x4 b1vv[4];
#pragma unroll
  for (int f = 0; f < 4; ++f) {
    float4 tw = *(const float4*)&W2[n * 64 + 16 * f + 4 * q];
    float4 tb = *(const float4*)&b1[n * 64 + 16 * f + 4 * q];
    w2A[f][0] = tw.x; w2A[f][1] = tw.y;
    w2B[f][0] = tw.z; w2B[f][1] = tw.w;
    b1vv[f][0] = tb.x; b1vv[f][1] = tb.y;
    b1vv[f][2] = tb.z; b1vv[f][3] = tb.w;
  }
  float bbl = b2[n] * -1.442695041f;  // bias pre-folded into exp2 fma

  // ---- stage raw rows: 12 rows x 256 cols -> rowsF[rf*RP + 4 + col] ----
  {
    int col = (t & 63) << 2;
#pragma unroll
    for (int it = 0; it < 3; ++it) {
      int rf = it * 4 + (t >> 6);  // 0..11
      int pl = (rf >= RPL) ? 1 : 0;
      int j  = rf - pl * RPL;
      int hh = h0 - 1 + j;
      const float* src = pl ? checkp : basep;
      float4 val = make_float4(0.f, 0.f, 0.f, 0.f);
      if ((unsigned)hh < (unsigned)Hn)
        val = *(const float4*)(src + hh * Wn + col);
      *(float4*)&rowsF[rf * RP + 4 + col] = val;
    }
    if (t < 12) {  // edge zeros
      rowsF[t * RP + 3] = 0.f;
      rowsF[t * RP + 260] = 0.f;
    }
    if (t >= 192) rowsF[ZW + (t - 192)] = 0.f;  // zero region (64 words)
  }

  // ---- per-lane gather bases: one address per group ----
  const unsigned int* rowsU = (const unsigned int*)rowsF;
  int g0pl = (q == 2) ? 1 : 0;
  int g0dx = (q == 0) ? 0 : (q == 1) ? 2 : 1;
  int g1pl = (q == 0) ? 0 : 1;
  int g1dx = (q == 0) ? 1 : (q == 1) ? 0 : 2;
  unsigned int addrG0, addrG1, step;
  if (q <= 2) {
    addrG0 = (unsigned)((g0pl * RPL) * RP + 3 + g0dx + wvid * 64 + m_);
    addrG1 = (unsigned)((g1pl * RPL) * RP + 3 + g1dx + wvid * 64 + m_);
    step = (unsigned)RP;
  } else {
    addrG0 = (unsigned)ZW;  // zero region; +s*16+16 <= +48 also zero
    addrG1 = (unsigned)ZW;
    step = 0u;
  }
  int bpaddr = ((lane ^ 32) << 2);  // ds_bpermute byte address for xor32

  __syncthreads();

  // A fragments (contiguous 16 B per lane, conflict-free)
  bf16x8 afrag[4];
#pragma unroll
  for (int f = 0; f < 4; ++f) afrag[f] = *(const bf16x8*)&wq[f][lane];

  float* combcc = comb + ((size_t)b * 7 + cc) * HW;
  int pxs = wvid * 64 + lane;
  bool bb1 = (lane & 32) != 0;
  bool bb0 = (lane & 16) != 0;

  // rolling tap registers: v{a,b}[rr][strip], statically indexed only
  unsigned int va[3][4], vb[3][4];
#pragma unroll
  for (int s = 0; s < 4; s += 2) {   // staged row 0 -> rr0
    va[0][s]     = rowsU[addrG0 + s * 16];
    va[0][s + 1] = rowsU[addrG0 + s * 16 + 16];
    vb[0][s]     = rowsU[addrG1 + s * 16];
    vb[0][s + 1] = rowsU[addrG1 + s * 16 + 16];
  }
  addrG0 += step; addrG1 += step;
#pragma unroll
  for (int s = 0; s < 4; s += 2) {   // staged row 1 -> rr1
    va[1][s]     = rowsU[addrG0 + s * 16];
    va[1][s + 1] = rowsU[addrG0 + s * 16 + 16];
    vb[1][s]     = rowsU[addrG1 + s * 16];
    vb[1][s + 1] = rowsU[addrG1 + s * 16 + 16];
  }
  addrG0 += step; addrG1 += step;

#pragma unroll 1
  for (int r = 0; r < ROWS; ++r) {
    float ccv = rowsF[(RPL + r + 1) * RP + 4 + pxs];  // check center

    // read new row (rr2): 4 ds_read2_b32
#pragma unroll
    for (int s = 0; s < 4; s += 2) {
      va[2][s]     = rowsU[addrG0 + s * 16];
      va[2][s + 1] = rowsU[addrG0 + s * 16 + 16];
      vb[2][s]     = rowsU[addrG1 + s * 16];
      vb[2][s + 1] = rowsU[addrG1 + s * 16 + 16];
    }
    addrG0 += step; addrG1 += step;

    float P[4];
#pragma unroll
    for (int sp = 0; sp < 2; ++sp) {
      int s0 = 2 * sp, s1 = 2 * sp + 1;
      union { unsigned int u[4]; bf16x8 v; } u0, u1;
      u0.u[0] = pk_bits(va[0][s0], va[1][s0]);
      u0.u[1] = pk_bits(va[2][s0], va[2][s0]);  // pad dup (A=0)
      u0.u[2] = pk_bits(vb[0][s0], vb[1][s0]);
      u0.u[3] = pk_bits(vb[2][s0], vb[2][s0]);
      u1.u[0] = pk_bits(va[0][s1], va[1][s1]);
      u1.u[1] = pk_bits(va[2][s1], va[2][s1]);
      u1.u[2] = pk_bits(vb[0][s1], vb[1][s1]);
      u1.u[3] = pk_bits(vb[2][s1], vb[2][s1]);

      f32x4 acc0[4], acc1[4];
#pragma unroll
      for (int f = 0; f < 4; ++f) {
        acc0[f] = __builtin_amdgcn_mfma_f32_16x16x32_bf16(afrag[f], u0.v,
                                                          b1vv[f], 0, 0, 0);
        acc1[f] = __builtin_amdgcn_mfma_f32_16x16x32_bf16(afrag[f], u1.v,
                                                          b1vv[f], 0, 0, 0);
      }
      f32x2 sA0 = {0.f, 0.f}, sB0 = {0.f, 0.f};
      f32x2 sA1 = {0.f, 0.f}, sB1 = {0.f, 0.f};
#pragma unroll
      for (int f = 0; f < 4; ++f) {
        f32x2 a01, a23, c01, c23;
        a01[0] = acc0[f][0]; a01[1] = acc0[f][1];
        a23[0] = acc0[f][2]; a23[1] = acc0[f][3];
        c01[0] = acc1[f][0]; c01[1] = acc1[f][1];
        c23[0] = acc1[f][2]; c23[1] = acc1[f][3];
        a01 = __builtin_elementwise_max(a01, (f32x2)0.f);
        a23 = __builtin_elementwise_max(a23, (f32x2)0.f);
        c01 = __builtin_elementwise_max(c01, (f32x2)0.f);
        c23 = __builtin_elementwise_max(c23, (f32x2)0.f);
        sA0 += w2A[f] * a01;
        sB0 += w2B[f] * a23;
        sA1 += w2A[f] * c01;
        sB1 += w2B[f] * c23;
      }
      f32x2 s0v = sA0 + sB0, s1v = sA1 + sB1;
      P[s0] = s0v[0] + s0v[1];
      P[s1] = s1v[0] + s1v[1];
    }

    // Butterfly transpose-reduce (verified): lane l ends with gate l>>4.
    float U0 = bb1 ? P[0] : P[2];
    float U1 = bb1 ? P[1] : P[3];
    float r0 = __int_as_float(
        __builtin_amdgcn_ds_bpermute(bpaddr, __float_as_int(U0)));
    float r1 = __int_as_float(
        __builtin_amdgcn_ds_bpermute(bpaddr, __float_as_int(U1)));
    float T0 = (bb1 ? P[2] : P[0]) + r0;
    float T1 = (bb1 ? P[3] : P[1]) + r1;
    float Wv = bb0 ? T0 : T1;
    float r2 = __int_as_float(
        __builtin_amdgcn_ds_swizzle(__float_as_int(Wv), 0x401F));
    float S = (bb0 ? T1 : T0) + r2;

    float e = __builtin_amdgcn_exp2f(fmaf(S, -1.442695041f, bbl));
    float g = __builtin_amdgcn_rcpf(1.f + e);
    combcc[(h0 + r) * Wn + pxs] = g * ccv;

    // rotate rolling registers (SSA renames)
#pragma unroll
    for (int s = 0; s < 4; ++s) {
      va[0][s] = va[1][s]; va[1][s] = va[2][s];
      vb[0][s] = vb[1][s]; vb[1][s] = vb[2][s];
    }
  }
}

// Kernel B (unchanged from R17): mix conv (7->7, 3x3, SAME), R13 geometry
// (512 blocks, 512 thr, 4-row chunks, LDS 44.4 KB) + packed v_pk_fma_f32.
__global__ __launch_bounds__(512) void mix_kernel(
    const float* __restrict__ comb,  // (8,7,256,256), plane 3 unused
    const float* __restrict__ x,     // (8,7,256,256), plane 3 = base
    const float* __restrict__ Wm,    // (7,7,3,3)
    const float* __restrict__ bm,    // (7,)
    float* __restrict__ out)         // (8,7,256,256)
{
  __shared__ float mr[42 * RP];  // 44.4 KB

  int bi = blockIdx.x;           // 0..511
  int b  = bi >> 6;
  int h0 = (bi & 63) << 2;
  int t = threadIdx.x;

  // stage: 42 rows (ic*6 + j) x 64 float4
  for (int u = t; u < 42 * 64; u += 512) {
    int rf = u >> 6;             // 0..41 = ic*6 + j
    int col = (u & 63) << 2;
    int ic = rf / 6, j = rf - ic * 6;
    int hh = h0 - 1 + j;
    const float* src = (ic == 3) ? (x + ((size_t)b * 7 + 3) * HW)
                                 : (comb + ((size_t)b * 7 + ic) * HW);
    float4 v = make_float4(0.f, 0.f, 0.f, 0.f);
    if ((unsigned)hh < (unsigned)Hn)
      v = *(const float4*)(src + hh * Wn + col);
    *(float4*)&mr[rf * RP + 4 + col] = v;
  }
  if (t < 42) {
    mr[t * RP + 3] = 0.f;
    mr[t * RP + 260] = 0.f;
  }
  __syncthreads();

  int r   = t >> 7;           // local row 0..3
  int px0 = (t & 127) << 1;   // 0..254
  int h   = h0 + r;

  f32x2 acc[7];
#pragma unroll
  for (int oc = 0; oc < 7; ++oc) {
    float bv = bm[oc];
    acc[oc] = (f32x2){bv, bv};
  }

#pragma unroll 1
  for (int ic = 0; ic < 7; ++ic) {
    // tap pairs: PP[dy][k] = (v_k, v_{k+1}), k=0..2, from 4 scalars
    f32x2 PP[3][3];
#pragma unroll
    for (int dy = 0; dy < 3; ++dy) {
      const float* rp = &mr[(ic * 6 + r + dy) * RP + 3 + px0];
      float v0 = rp[0], v1 = rp[1], v2 = rp[2], v3 = rp[3];
      PP[dy][0] = (f32x2){v0, v1};
      PP[dy][1] = (f32x2){v1, v2};
      PP[dy][2] = (f32x2){v2, v3};
    }
    const float* wp = Wm + ic * 9;
#pragma unroll
    for (int oc = 0; oc < 7; ++oc) {
      const float* wo = wp + oc * 63;
#pragma unroll
      for (int dy = 0; dy < 3; ++dy) {
        float w0 = wo[dy * 3], w1 = wo[dy * 3 + 1], w2 = wo[dy * 3 + 2];
        acc[oc] = fma2(w0, PP[dy][0],
                   fma2(w1, PP[dy][1], fma2(w2, PP[dy][2], acc[oc])));
      }
    }
  }

  float* ob = out + (size_t)b * 7 * HW + h * Wn + px0;
#pragma unroll
  for (int oc = 0; oc < 7; ++oc)
    *(float2*)(ob + (size_t)oc * HW) = make_float2(acc[oc][0], acc[oc][1]);
}

extern "C" void kernel_launch(void* const* d_in, const int* in_sizes, int n_in,
                              void* d_out, int out_size, void* d_ws, size_t ws_size,
                              hipStream_t stream) {
  const float* x  = (const float*)d_in[0];
  const float* W1 = (const float*)d_in[1];
  const float* b1 = (const float*)d_in[2];
  const float* W2 = (const float*)d_in[3];
  const float* b2 = (const float*)d_in[4];
  const float* Wm = (const float*)d_in[5];
  const float* bm = (const float*)d_in[6];
  float* out  = (float*)d_out;
  float* comb = (float*)d_ws;  // 8*7*256*256 floats = 14.7 MB

  sim_kernel<<<6 * 8 * (Hn / ROWS), 256, 0, stream>>>(x, W1, b1, W2, b2, comb);
  mix_kernel<<<8 * (Hn / 4), 512, 0, stream>>>(comb, x, Wm, bm, out);
}

// Round 10
// 110.719 us; speedup vs baseline: 8.6203x; 1.0186x over previous
//
#include <hip/hip_runtime.h>
#include <math.h>

#define Bn 8
#define Hn 256
#define Wn 256
#define HW (Hn * Wn)
#define ROWS 4
#define RPL 6        // pair-frames per plane (j=0..5)
#define RP 264       // padded row length (words); data at [4..259]
#define PO (RPL*RP)  // plane offset 1584 == 16 (mod 32) -> bank pairing
#define ZW (12 * RP) // zero region: pairU[ZW .. ZW+63] == 0

typedef __attribute__((ext_vector_type(8))) short bf16x8;
typedef __attribute__((ext_vector_type(4))) float f32x4;
typedef __attribute__((ext_vector_type(2))) float f32x2;

__device__ __forceinline__ unsigned int pk_bits(unsigned int lo,
                                                unsigned int hi) {
  return __builtin_amdgcn_perm(hi, lo, 0x07060302u);
}
__device__ __forceinline__ unsigned int pk_bf16(float lo, float hi) {
  return pk_bits(__float_as_uint(lo), __float_as_uint(hi));
}
// packed fma: c + {s,s}*a  (fp-contract -> v_pk_fma_f32)
__device__ __forceinline__ f32x2 fma2(float s, f32x2 a, f32x2 c) {
  f32x2 sv = {s, s};
  return sv * a + c;
}

// R18/R19 k-slot map: lane q owns two (pl,dx) groups, rr in consecutive
// slots: q0: g0=(pl0,dx0) g1=(pl0,dx1); q1: g0=(pl0,dx2) g1=(pl1,dx0);
// q2: g0=(pl1,dx1) g1=(pl1,dx2); q3 + slots jh3/jh7: dead (A-weight 0).

// Kernel A (R19): vertically PRE-PACKED bf16-pair LDS.
// R18 post-mortem: -60% gather DS -> -0.4us (noise) => not DS-bound; R17's
// win re-attributed to mix's VALU cut. Only VALU slot count has ever moved
// the needle. This round deletes sim's per-row B-build VALU entirely:
//   pairU[pl][j][px] = pk_bf16(frame j, frame j+1)  (staged once)
//   B-reg0 = pairU[r], B-reg1 = pairU[r+2] (hi half killed by A=0 pad)
//   all 24 ds_read2 up-front into 48 static regs; ROWS fully unrolled
//   (no rotations, no perms); ccv from global f32 (-4 DS).
// Numerics identical (same truncation, same fma order).
__global__ __launch_bounds__(256, 3) void sim_kernel(
    const float* __restrict__ x,   // (8,7,256,256)
    const float* __restrict__ W1,  // (6,64,2,3,3)
    const float* __restrict__ b1,  // (6,64)
    const float* __restrict__ W2,  // (6,1,64,1,1)
    const float* __restrict__ b2,  // (6,1)
    float* __restrict__ comb)      // (8,7,256,256)
{
  __shared__ unsigned int pairU[12 * RP + 64];  // 12.9 KB packed pairs
  __shared__ uint4 wq[4][64];                   // 4 KB A-frags

  int bi = blockIdx.x;
  int n  = bi >> 9;            // 0..5  (512 blocks per n)
  int b  = (bi >> 6) & 7;      // 0..7
  int h0 = (bi & 63) * ROWS;   // chunk start row
  int cc = (n < 3) ? n : n + 1;
  int t = threadIdx.x;

  const float* xb     = x + (size_t)b * 7 * HW;
  const float* basep  = xb + 3 * HW;
  const float* checkp = xb + (size_t)cc * HW;

  // ---- stage weights in MFMA A-layout (R18 slot map) ----
  {
    int f = t >> 6, qq = (t >> 4) & 3, m = t & 15;
    int bsrc = (n < 3) ? 0 : 1;  // weight input-ch that multiplies BASE
    const float* wch = W1 + ((size_t)(n * 64 + 16 * f + m)) * 18;
    int g0pl = (qq == 2) ? 1 : 0;
    int g0dx = (qq == 0) ? 0 : (qq == 1) ? 2 : 1;
    int g1pl = (qq == 0) ? 0 : 1;
    int g1dx = (qq == 0) ? 1 : (qq == 1) ? 0 : 2;
    float wg0[3], wg1[3];
#pragma unroll
    for (int rrs = 0; rrs < 3; ++rrs) {
      wg0[rrs] = (qq <= 2)
          ? wch[(g0pl ? 1 - bsrc : bsrc) * 9 + rrs * 3 + g0dx] : 0.f;
      wg1[rrs] = (qq <= 2)
          ? wch[(g1pl ? 1 - bsrc : bsrc) * 9 + rrs * 3 + g1dx] : 0.f;
    }
    unsigned int kv[4];
    kv[0] = pk_bf16(wg0[0], wg0[1]);
    kv[1] = pk_bf16(wg0[2], 0.f);     // pad slot jh3: A = 0
    kv[2] = pk_bf16(wg1[0], wg1[1]);
    kv[3] = pk_bf16(wg1[2], 0.f);     // pad slot jh7: A = 0
    wq[f][(qq << 4) + m] = make_uint4(kv[0], kv[1], kv[2], kv[3]);
  }

  // ---- per-lane conv2/bias params (global loads, no LDS dep) ----
  int lane = t & 63, wvid = t >> 6;
  int q = lane >> 4, m_ = lane & 15;
  f32x2 w2A[4], w2B[4];
  f32x4 b1vv[4];
#pragma unroll
  for (int f = 0; f < 4; ++f) {
    float4 tw = *(const float4*)&W2[n * 64 + 16 * f + 4 * q];
    float4 tb = *(const float4*)&b1[n * 64 + 16 * f + 4 * q];
    w2A[f][0] = tw.x; w2A[f][1] = tw.y;
    w2B[f][0] = tw.z; w2B[f][1] = tw.w;
    b1vv[f][0] = tb.x; b1vv[f][1] = tb.y;
    b1vv[f][2] = tb.z; b1vv[f][3] = tb.w;
  }
  float bbl = b2[n] * -1.442695041f;  // bias pre-folded into exp2 fma

  // ---- stage packed pairs: 12 frames (pl*6+j) x 256 px ----
  // pairU[rf*RP + 4 + px] = pk(row h0-1+j, row h0+j) at px; j=5 hi = 0.
  {
    int col = (t & 63) << 2;
#pragma unroll
    for (int it = 0; it < 3; ++it) {
      int rf = it * 4 + (t >> 6);  // 0..11
      int pl = (rf >= RPL) ? 1 : 0;
      int j  = rf - pl * RPL;
      const float* src = pl ? checkp : basep;
      int hlo = h0 - 1 + j, hhi = h0 + j;
      float4 vlo = make_float4(0.f, 0.f, 0.f, 0.f);
      float4 vhi = make_float4(0.f, 0.f, 0.f, 0.f);
      if ((unsigned)hlo < (unsigned)Hn)
        vlo = *(const float4*)(src + hlo * Wn + col);
      if ((unsigned)hhi < (unsigned)Hn)
        vhi = *(const float4*)(src + hhi * Wn + col);
      uint4 pk;
      pk.x = pk_bf16(vlo.x, vhi.x);
      pk.y = pk_bf16(vlo.y, vhi.y);
      pk.z = pk_bf16(vlo.z, vhi.z);
      pk.w = pk_bf16(vlo.w, vhi.w);
      *(uint4*)&pairU[rf * RP + 4 + col] = pk;
    }
    if (t < 12) {  // edge zeros (dx = -1 / +1 reach)
      pairU[t * RP + 3] = 0u;
      pairU[t * RP + 260] = 0u;
    }
    if (t >= 192) pairU[ZW + (t - 192)] = 0u;  // dead-lane region
  }

  // ---- per-lane gather bases (one per group) ----
  int g0pl = (q == 2) ? 1 : 0;
  int g0dx = (q == 0) ? 0 : (q == 1) ? 2 : 1;
  int g1pl = (q == 0) ? 0 : 1;
  int g1dx = (q == 0) ? 1 : (q == 1) ? 0 : 2;
  unsigned int aG0, aG1, stepv;
  if (q <= 2) {
    aG0 = (unsigned)(g0pl * PO + 3 + g0dx + wvid * 64 + m_);
    aG1 = (unsigned)(g1pl * PO + 3 + g1dx + wvid * 64 + m_);
    stepv = (unsigned)RP;
  } else {
    aG0 = (unsigned)ZW;  // + s*16 <= +48, still zero region
    aG1 = (unsigned)ZW;
    stepv = 0u;
  }
  int bpaddr = ((lane ^ 32) << 2);  // ds_bpermute byte address for xor32

  __syncthreads();

  // A fragments (contiguous 16 B per lane, conflict-free)
  bf16x8 afrag[4];
#pragma unroll
  for (int f = 0; f < 4; ++f) afrag[f] = *(const bf16x8*)&wq[f][lane];

  float* combcc = comb + ((size_t)b * 7 + cc) * HW;
  int pxs = wvid * 64 + lane;
  bool bb1 = (lane & 32) != 0;
  bool bb0 = (lane & 16) != 0;

  // ---- all gathers up-front: 6 pair-frames x 2 groups x 4 strips ----
  // (static indices only -> registers; 24 ds_read2_b32 total)
  unsigned int Pj[6][2][4];
#pragma unroll
  for (int j = 0; j < 6; ++j) {
    unsigned int a0 = aG0 + j * stepv, a1 = aG1 + j * stepv;
#pragma unroll
    for (int s = 0; s < 4; ++s) {
      Pj[j][0][s] = pairU[a0 + s * 16];
      Pj[j][1][s] = pairU[a1 + s * 16];
    }
  }

#pragma unroll
  for (int r = 0; r < ROWS; ++r) {
    float ccv = checkp[(h0 + r) * Wn + pxs];  // f32 center (global, exact)

    float P[4];
#pragma unroll
    for (int sp = 0; sp < 2; ++sp) {
      int s0 = 2 * sp, s1 = s0 + 1;
      union { unsigned int u[4]; bf16x8 v; } u0, u1;
      u0.u[0] = Pj[r][0][s0];     u0.u[1] = Pj[r + 2][0][s0];
      u0.u[2] = Pj[r][1][s0];     u0.u[3] = Pj[r + 2][1][s0];
      u1.u[0] = Pj[r][0][s1];     u1.u[1] = Pj[r + 2][0][s1];
      u1.u[2] = Pj[r][1][s1];     u1.u[3] = Pj[r + 2][1][s1];

      f32x4 acc0[4], acc1[4];
#pragma unroll
      for (int f = 0; f < 4; ++f) {
        acc0[f] = __builtin_amdgcn_mfma_f32_16x16x32_bf16(afrag[f], u0.v,
                                                          b1vv[f], 0, 0, 0);
        acc1[f] = __builtin_amdgcn_mfma_f32_16x16x32_bf16(afrag[f], u1.v,
                                                          b1vv[f], 0, 0, 0);
      }
      f32x2 sA0 = {0.f, 0.f}, sB0 = {0.f, 0.f};
      f32x2 sA1 = {0.f, 0.f}, sB1 = {0.f, 0.f};
#pragma unroll
      for (int f = 0; f < 4; ++f) {
        f32x2 a01, a23, c01, c23;
        a01[0] = acc0[f][0]; a01[1] = acc0[f][1];
        a23[0] = acc0[f][2]; a23[1] = acc0[f][3];
        c01[0] = acc1[f][0]; c01[1] = acc1[f][1];
        c23[0] = acc1[f][2]; c23[1] = acc1[f][3];
        a01 = __builtin_elementwise_max(a01, (f32x2)0.f);
        a23 = __builtin_elementwise_max(a23, (f32x2)0.f);
        c01 = __builtin_elementwise_max(c01, (f32x2)0.f);
        c23 = __builtin_elementwise_max(c23, (f32x2)0.f);
        sA0 += w2A[f] * a01;
        sB0 += w2B[f] * a23;
        sA1 += w2A[f] * c01;
        sB1 += w2B[f] * c23;
      }
      f32x2 s0v = sA0 + sB0, s1v = sA1 + sB1;
      P[s0] = s0v[0] + s0v[1];
      P[s1] = s1v[0] + s1v[1];
    }

    // Butterfly transpose-reduce (verified): lane l ends with gate l>>4.
    float U0 = bb1 ? P[0] : P[2];
    float U1 = bb1 ? P[1] : P[3];
    float r0 = __int_as_float(
        __builtin_amdgcn_ds_bpermute(bpaddr, __float_as_int(U0)));
    float r1 = __int_as_float(
        __builtin_amdgcn_ds_bpermute(bpaddr, __float_as_int(U1)));
    float T0 = (bb1 ? P[2] : P[0]) + r0;
    float T1 = (bb1 ? P[3] : P[1]) + r1;
    float Wv = bb0 ? T0 : T1;
    float r2 = __int_as_float(
        __builtin_amdgcn_ds_swizzle(__float_as_int(Wv), 0x401F));
    float S = (bb0 ? T1 : T0) + r2;

    float e = __builtin_amdgcn_exp2f(fmaf(S, -1.442695041f, bbl));
    float g = __builtin_amdgcn_rcpf(1.f + e);
    combcc[(h0 + r) * Wn + pxs] = g * ccv;
  }
}

// Kernel B (unchanged from R17/R18): mix conv (7->7, 3x3, SAME), R13
// geometry (512 blocks, 512 thr, 4-row chunks, LDS 44.4 KB) + packed
// v_pk_fma_f32.
__global__ __launch_bounds__(512) void mix_kernel(
    const float* __restrict__ comb,  // (8,7,256,256), plane 3 unused
    const float* __restrict__ x,     // (8,7,256,256), plane 3 = base
    const float* __restrict__ Wm,    // (7,7,3,3)
    const float* __restrict__ bm,    // (7,)
    float* __restrict__ out)         // (8,7,256,256)
{
  __shared__ float mr[42 * RP];  // 44.4 KB

  int bi = blockIdx.x;           // 0..511
  int b  = bi >> 6;
  int h0 = (bi & 63) << 2;
  int t = threadIdx.x;

  // stage: 42 rows (ic*6 + j) x 64 float4
  for (int u = t; u < 42 * 64; u += 512) {
    int rf = u >> 6;             // 0..41 = ic*6 + j
    int col = (u & 63) << 2;
    int ic = rf / 6, j = rf - ic * 6;
    int hh = h0 - 1 + j;
    const float* src = (ic == 3) ? (x + ((size_t)b * 7 + 3) * HW)
                                 : (comb + ((size_t)b * 7 + ic) * HW);
    float4 v = make_float4(0.f, 0.f, 0.f, 0.f);
    if ((unsigned)hh < (unsigned)Hn)
      v = *(const float4*)(src + hh * Wn + col);
    *(float4*)&mr[rf * RP + 4 + col] = v;
  }
  if (t < 42) {
    mr[t * RP + 3] = 0.f;
    mr[t * RP + 260] = 0.f;
  }
  __syncthreads();

  int r   = t >> 7;           // local row 0..3
  int px0 = (t & 127) << 1;   // 0..254
  int h   = h0 + r;

  f32x2 acc[7];
#pragma unroll
  for (int oc = 0; oc < 7; ++oc) {
    float bv = bm[oc];
    acc[oc] = (f32x2){bv, bv};
  }

#pragma unroll 1
  for (int ic = 0; ic < 7; ++ic) {
    // tap pairs: PP[dy][k] = (v_k, v_{k+1}), k=0..2, from 4 scalars
    f32x2 PP[3][3];
#pragma unroll
    for (int dy = 0; dy < 3; ++dy) {
      const float* rp = &mr[(ic * 6 + r + dy) * RP + 3 + px0];
      float v0 = rp[0], v1 = rp[1], v2 = rp[2], v3 = rp[3];
      PP[dy][0] = (f32x2){v0, v1};
      PP[dy][1] = (f32x2){v1, v2};
      PP[dy][2] = (f32x2){v2, v3};
    }
    const float* wp = Wm + ic * 9;
#pragma unroll
    for (int oc = 0; oc < 7; ++oc) {
      const float* wo = wp + oc * 63;
#pragma unroll
      for (int dy = 0; dy < 3; ++dy) {
        float w0 = wo[dy * 3], w1 = wo[dy * 3 + 1], w2 = wo[dy * 3 + 2];
        acc[oc] = fma2(w0, PP[dy][0],
                   fma2(w1, PP[dy][1], fma2(w2, PP[dy][2], acc[oc])));
      }
    }
  }

  float* ob = out + (size_t)b * 7 * HW + h * Wn + px0;
#pragma unroll
  for (int oc = 0; oc < 7; ++oc)
    *(float2*)(ob + (size_t)oc * HW) = make_float2(acc[oc][0], acc[oc][1]);
}

extern "C" void kernel_launch(void* const* d_in, const int* in_sizes, int n_in,
                              void* d_out, int out_size, void* d_ws, size_t ws_size,
                              hipStream_t stream) {
  const float* x  = (const float*)d_in[0];
  const float* W1 = (const float*)d_in[1];
  const float* b1 = (const float*)d_in[2];
  const float* W2 = (const float*)d_in[3];
  const float* b2 = (const float*)d_in[4];
  const float* Wm = (const float*)d_in[5];
  const float* bm = (const float*)d_in[6];
  float* out  = (float*)d_out;
  float* comb = (float*)d_ws;  // 8*7*256*256 floats = 14.7 MB

  sim_kernel<<<6 * 8 * (Hn / ROWS), 256, 0, stream>>>(x, W1, b1, W2, b2, comb);
  mix_kernel<<<8 * (Hn / 4), 512, 0, stream>>>(comb, x, Wm, bm, out);
}